// Round 1
// baseline (792.674 us; speedup 1.0000x reference)
//
#include <hip/hip_runtime.h>
#include <cstddef>

#define NB_HEAD 16
#define HEAD_DIM 64
#define D_MODEL 1024
#define BATCH 2
#define SEQ 2048

// ---------------------------------------------------------------------------
// Projection GEMM: out[b][h][l][d] = sum_k X[b*SEQ+l][k] * W[k][h*64+d]
// 64x64 output tile per block, BK=16, 256 threads, 4x4 microtile.
// Output written directly in [B][H][L][64] layout for the attention kernel.
// ---------------------------------------------------------------------------
__global__ __launch_bounds__(256) void proj_kernel(
    const float* __restrict__ X, const float* __restrict__ W,
    float* __restrict__ out)
{
    __shared__ __align__(16) float As[16][68];  // [k][m] (transposed)
    __shared__ __align__(16) float Bs[16][68];  // [k][n]

    const int tid = threadIdx.x;
    const int tx = tid & 15, ty = tid >> 4;
    const int m0 = blockIdx.y * 64;
    const int n0 = blockIdx.x * 64;

    const int lr = tid >> 2;        // 0..63  A row within tile
    const int lc = (tid & 3) * 4;   // 0,4,8,12  A col seg
    const int wr = tid >> 4;        // 0..15  W row within tile
    const int wc = (tid & 15) * 4;  // W col seg

    float c[4][4] = {};

    for (int k0 = 0; k0 < D_MODEL; k0 += 16) {
        const float4 a4 = *(const float4*)(X + (size_t)(m0 + lr) * D_MODEL + k0 + lc);
        const float4 b4 = *(const float4*)(W + (size_t)(k0 + wr) * D_MODEL + n0 + wc);
        As[lc + 0][lr] = a4.x;
        As[lc + 1][lr] = a4.y;
        As[lc + 2][lr] = a4.z;
        As[lc + 3][lr] = a4.w;
        *(float4*)(&Bs[wr][wc]) = b4;
        __syncthreads();
        #pragma unroll
        for (int kk = 0; kk < 16; ++kk) {
            const float4 av = *(const float4*)(&As[kk][ty * 4]);
            const float4 bv = *(const float4*)(&Bs[kk][tx * 4]);
            const float aa[4] = {av.x, av.y, av.z, av.w};
            const float bb[4] = {bv.x, bv.y, bv.z, bv.w};
            #pragma unroll
            for (int i = 0; i < 4; ++i)
                #pragma unroll
                for (int j = 0; j < 4; ++j)
                    c[i][j] = fmaf(aa[i], bb[j], c[i][j]);
        }
        __syncthreads();
    }

    // Permuted write: row m -> (b, l), col n -> (h, d)
    const int h = n0 >> 6;   // tile is 64-col aligned: one head per block
    #pragma unroll
    for (int i = 0; i < 4; ++i) {
        const int mg = m0 + ty * 4 + i;
        const int bb = mg >> 11;          // / SEQ
        const int l  = mg & (SEQ - 1);
        const float4 r4 = make_float4(c[i][0], c[i][1], c[i][2], c[i][3]);
        *(float4*)(out + (((size_t)bb * NB_HEAD + h) * SEQ + l) * HEAD_DIM + tx * 4) = r4;
    }
}

// ---------------------------------------------------------------------------
// Flash-style attention, fp32. One block = 64 query rows of one (b,h).
// Key tiles of 64; tiles past v_len skipped (exact: ref's -1e12 underflows
// exp to 0 in fp32). Rows >= q_len written as zeros (ref's mult. mask).
// LDS: Qs transposed [d][row], KVs dual-use (K transposed / V natural),
// Ss scores->probs. 53 KB total.
// ---------------------------------------------------------------------------
__global__ __launch_bounds__(256) void attn_kernel(
    const float* __restrict__ q, const float* __restrict__ k,
    const float* __restrict__ v, const int* __restrict__ q_len,
    const int* __restrict__ v_len, float* __restrict__ out)
{
    __shared__ __align__(16) float Qs[64][68];   // [d][qrow]
    __shared__ __align__(16) float KVs[64][68];  // K phase: [d][kcol]; V phase: [krow][d]
    __shared__ __align__(16) float Ss[64][68];   // [qrow][kcol]
    __shared__ float m_row[64], l_row[64], a_row[64];

    const int tid = threadIdx.x;
    const int tx = tid & 15, ty = tid >> 4;
    const int q0 = blockIdx.x * 64;
    const int h  = blockIdx.y;
    const int b  = blockIdx.z;
    const int qlen = q_len[b];
    const int vlen = v_len[b];

    float* outb = out + ((size_t)b * SEQ) * D_MODEL + h * HEAD_DIM + tx * 4;

    if (q0 >= qlen) {  // whole chunk masked: write zeros, done (uniform branch)
        const float4 z = make_float4(0.f, 0.f, 0.f, 0.f);
        #pragma unroll
        for (int i = 0; i < 4; ++i)
            *(float4*)(outb + (size_t)(q0 + ty * 4 + i) * D_MODEL) = z;
        return;
    }

    const size_t headoff = (((size_t)b * NB_HEAD + h) * SEQ) * HEAD_DIM;
    const float* qb = q + headoff;
    const float* kb = k + headoff;
    const float* vb = v + headoff;

    const int lr = tid >> 2;        // 0..63 row for cooperative loads
    const int lc = (tid & 3) * 16;  // 0,16,32,48 col seg

    // Q tile -> LDS transposed
    {
        const float* qrow = qb + (size_t)(q0 + lr) * HEAD_DIM + lc;
        #pragma unroll
        for (int u = 0; u < 4; ++u) {
            const float4 t4 = *(const float4*)(qrow + u * 4);
            Qs[lc + u * 4 + 0][lr] = t4.x;
            Qs[lc + u * 4 + 1][lr] = t4.y;
            Qs[lc + u * 4 + 2][lr] = t4.z;
            Qs[lc + u * 4 + 3][lr] = t4.w;
        }
    }
    if (tid < 64) { m_row[tid] = -1e30f; l_row[tid] = 0.f; }

    float o[4][4] = {};
    const int nkt = (vlen + 63) >> 6;

    for (int t = 0; t < nkt; ++t) {
        const int k0 = t * 64;
        __syncthreads();  // prev PV done before KVs/Ss overwrite (also covers Q/stats init)

        // K tile -> LDS transposed
        {
            const float* krow = kb + (size_t)(k0 + lr) * HEAD_DIM + lc;
            #pragma unroll
            for (int u = 0; u < 4; ++u) {
                const float4 t4 = *(const float4*)(krow + u * 4);
                KVs[lc + u * 4 + 0][lr] = t4.x;
                KVs[lc + u * 4 + 1][lr] = t4.y;
                KVs[lc + u * 4 + 2][lr] = t4.z;
                KVs[lc + u * 4 + 3][lr] = t4.w;
            }
        }
        __syncthreads();

        // S = (Q K^T) * 1/8, mask cols >= vlen
        float s[4][4] = {};
        for (int d = 0; d < 64; ++d) {
            const float4 qv = *(const float4*)(&Qs[d][ty * 4]);
            const float4 kv = *(const float4*)(&KVs[d][tx * 4]);
            const float qa[4] = {qv.x, qv.y, qv.z, qv.w};
            const float ka[4] = {kv.x, kv.y, kv.z, kv.w};
            #pragma unroll
            for (int i = 0; i < 4; ++i)
                #pragma unroll
                for (int j = 0; j < 4; ++j)
                    s[i][j] = fmaf(qa[i], ka[j], s[i][j]);
        }
        #pragma unroll
        for (int i = 0; i < 4; ++i)
            #pragma unroll
            for (int j = 0; j < 4; ++j) {
                float val = s[i][j] * 0.125f;
                if (k0 + tx * 4 + j >= vlen) val = -1e30f;
                Ss[ty * 4 + i][tx * 4 + j] = val;
            }
        __syncthreads();  // S complete; KVs free for V

        // V tile -> LDS natural (overwrites K)
        {
            const float* vrow = vb + (size_t)(k0 + lr) * HEAD_DIM + lc;
            #pragma unroll
            for (int u = 0; u < 4; ++u)
                *(float4*)(&KVs[lr][lc + u * 4]) = *(const float4*)(vrow + u * 4);
        }

        // Online softmax: 4 lanes per query row (row = tid>>2)
        {
            const int r = tid >> 2;
            const int seg = (tid & 3) * 16;
            float vals[16];
            float mx = -1e30f;
            #pragma unroll
            for (int u = 0; u < 4; ++u) {
                const float4 t4 = *(const float4*)(&Ss[r][seg + u * 4]);
                vals[u * 4 + 0] = t4.x; vals[u * 4 + 1] = t4.y;
                vals[u * 4 + 2] = t4.z; vals[u * 4 + 3] = t4.w;
            }
            #pragma unroll
            for (int u = 0; u < 16; ++u) mx = fmaxf(mx, vals[u]);
            mx = fmaxf(mx, __shfl_xor(mx, 1));
            mx = fmaxf(mx, __shfl_xor(mx, 2));
            const float mold = m_row[r];
            const float mnew = fmaxf(mold, mx);
            float sum = 0.f;
            #pragma unroll
            for (int u = 0; u < 16; ++u) { vals[u] = __expf(vals[u] - mnew); sum += vals[u]; }
            #pragma unroll
            for (int u = 0; u < 4; ++u)
                *(float4*)(&Ss[r][seg + u * 4]) =
                    make_float4(vals[u * 4 + 0], vals[u * 4 + 1], vals[u * 4 + 2], vals[u * 4 + 3]);
            sum += __shfl_xor(sum, 1);
            sum += __shfl_xor(sum, 2);
            if ((tid & 3) == 0) {
                const float alpha = __expf(mold - mnew);
                a_row[r] = alpha;
                l_row[r] = l_row[r] * alpha + sum;
                m_row[r] = mnew;
            }
        }
        __syncthreads();

        // O = O*alpha + P V
        {
            const float al[4] = {a_row[ty * 4 + 0], a_row[ty * 4 + 1],
                                 a_row[ty * 4 + 2], a_row[ty * 4 + 3]};
            #pragma unroll
            for (int i = 0; i < 4; ++i)
                #pragma unroll
                for (int j = 0; j < 4; ++j)
                    o[i][j] *= al[i];
            for (int kk = 0; kk < 64; kk += 4) {
                float4 p[4], vv[4];
                #pragma unroll
                for (int i = 0; i < 4; ++i) p[i] = *(const float4*)(&Ss[ty * 4 + i][kk]);
                #pragma unroll
                for (int u = 0; u < 4; ++u) vv[u] = *(const float4*)(&KVs[kk + u][tx * 4]);
                #pragma unroll
                for (int i = 0; i < 4; ++i) {
                    const float pa[4] = {p[i].x, p[i].y, p[i].z, p[i].w};
                    #pragma unroll
                    for (int u = 0; u < 4; ++u) {
                        o[i][0] = fmaf(pa[u], vv[u].x, o[i][0]);
                        o[i][1] = fmaf(pa[u], vv[u].y, o[i][1]);
                        o[i][2] = fmaf(pa[u], vv[u].z, o[i][2]);
                        o[i][3] = fmaf(pa[u], vv[u].w, o[i][3]);
                    }
                }
            }
        }
    }

    // Epilogue: normalize, apply query mask, write
    #pragma unroll
    for (int i = 0; i < 4; ++i) {
        const int r = ty * 4 + i;
        const int qg = q0 + r;
        float4 r4;
        if (qg < qlen) {
            const float inv = 1.f / l_row[r];
            r4 = make_float4(o[i][0] * inv, o[i][1] * inv, o[i][2] * inv, o[i][3] * inv);
        } else {
            r4 = make_float4(0.f, 0.f, 0.f, 0.f);
        }
        *(float4*)(outb + (size_t)qg * D_MODEL) = r4;
    }
}

extern "C" void kernel_launch(void* const* d_in, const int* in_sizes, int n_in,
                              void* d_out, int out_size, void* d_ws, size_t ws_size,
                              hipStream_t stream)
{
    (void)in_sizes; (void)n_in; (void)out_size; (void)ws_size;
    const float* Q_seq = (const float*)d_in[0];
    const float* K_seq = (const float*)d_in[1];
    const float* V_seq = (const float*)d_in[2];
    const int*   q_len = (const int*)d_in[3];
    const int*   v_len = (const int*)d_in[4];
    const float* WQ    = (const float*)d_in[5];
    const float* WK    = (const float*)d_in[6];
    const float* WV    = (const float*)d_in[7];
    float* out = (float*)d_out;

    // Workspace: q,k,v in [B][H][L][64] fp32 — 3 x 16 MB = 48 MB
    const size_t per = (size_t)BATCH * NB_HEAD * SEQ * HEAD_DIM;
    float* qw = (float*)d_ws;
    float* kw = qw + per;
    float* vw = kw + per;

    dim3 blk(256);
    dim3 pg(D_MODEL / 64, (BATCH * SEQ) / 64);  // (16, 64)
    proj_kernel<<<pg, blk, 0, stream>>>(Q_seq, WQ, qw);
    proj_kernel<<<pg, blk, 0, stream>>>(K_seq, WK, kw);
    proj_kernel<<<pg, blk, 0, stream>>>(V_seq, WV, vw);

    dim3 ag(SEQ / 64, NB_HEAD, BATCH);          // (32, 16, 2)
    attn_kernel<<<ag, blk, 0, stream>>>(qw, kw, vw, q_len, v_len, out);
}

// Round 2
// 512.170 us; speedup vs baseline: 1.5477x; 1.5477x over previous
//
#include <hip/hip_runtime.h>
#include <cstddef>
#include <cstdint>

#define NB_HEAD 16
#define HEAD_DIM 64
#define D_MODEL 1024
#define BATCH 2
#define SEQ 2048
#define MROWS (BATCH * SEQ)  // 4096

typedef __bf16 bf16x8 __attribute__((ext_vector_type(8)));
typedef float  f32x4  __attribute__((ext_vector_type(4)));

static __device__ __forceinline__ unsigned short f2bf_rn(float x) {
    unsigned u = __float_as_uint(x);
    u += 0x7FFF + ((u >> 16) & 1);   // round-to-nearest-even
    return (unsigned short)(u >> 16);
}
static __device__ __forceinline__ float bf2f(unsigned short h) {
    return __uint_as_float(((unsigned)h) << 16);
}

// ---------------------------------------------------------------------------
// W[K][N] fp32  ->  Wt_hi[N][K], Wt_lo[N][K] bf16 (split precision), per z.
// 64x64 transpose tiles through LDS.
// ---------------------------------------------------------------------------
__global__ __launch_bounds__(256) void conv_wt_kernel(
    const float* __restrict__ W0, const float* __restrict__ W1,
    const float* __restrict__ W2,
    unsigned short* __restrict__ hi, unsigned short* __restrict__ lo)
{
    __shared__ float tile[64][65];
    const int t  = threadIdx.x;
    const int k0 = blockIdx.x * 64;  // input row block (K)
    const int n0 = blockIdx.y * 64;  // input col block (N)
    const int z  = blockIdx.z;
    const float* W = (z == 0) ? W0 : ((z == 1) ? W1 : W2);
    unsigned short* hz = hi + (size_t)z * D_MODEL * D_MODEL;
    unsigned short* lz = lo + (size_t)z * D_MODEL * D_MODEL;

    #pragma unroll
    for (int p = 0; p < 4; ++p) {
        const int e = (p * 256 + t) * 4;
        const int r = e >> 6, c = e & 63;
        const float4 v = *(const float4*)(W + (size_t)(k0 + r) * D_MODEL + n0 + c);
        tile[r][c] = v.x; tile[r][c + 1] = v.y; tile[r][c + 2] = v.z; tile[r][c + 3] = v.w;
    }
    __syncthreads();
    #pragma unroll
    for (int p = 0; p < 4; ++p) {
        const int e = (p * 256 + t) * 4;
        const int n = e >> 6, kc = e & 63;
        unsigned short h[4], l[4];
        #pragma unroll
        for (int u = 0; u < 4; ++u) {
            const float x = tile[kc + u][n];
            h[u] = f2bf_rn(x);
            l[u] = f2bf_rn(x - bf2f(h[u]));
        }
        *(ushort4*)(hz + (size_t)(n0 + n) * D_MODEL + k0 + kc) = make_ushort4(h[0], h[1], h[2], h[3]);
        *(ushort4*)(lz + (size_t)(n0 + n) * D_MODEL + k0 + kc) = make_ushort4(l[0], l[1], l[2], l[3]);
    }
}

// ---------------------------------------------------------------------------
// Split-bf16 MFMA projection: out[b][h][l][d] = X[m][k] W[k][n] with
// C = Xhi Whi + Xhi Wlo + Xlo Whi  (fp32-grade accuracy on the MFMA pipe).
// 128x128 tile, BK=32, 256 thr (4 waves, each 64x64 via 4x4 16x16x32 tiles).
// A staged fp32->hi/lo via VALU; B staged via global_load_lds from Wt hi/lo.
// ---------------------------------------------------------------------------
__global__ __launch_bounds__(256) void proj_mfma_kernel(
    const float* __restrict__ X0, const float* __restrict__ X1,
    const float* __restrict__ X2,
    const unsigned short* __restrict__ Wthi,
    const unsigned short* __restrict__ Wtlo,
    float* __restrict__ out)
{
    __shared__ __align__(16) unsigned short Ahi[128 * 32];
    __shared__ __align__(16) unsigned short Alo[128 * 32];
    __shared__ __align__(16) unsigned short Bhi[128 * 32];
    __shared__ __align__(16) unsigned short Blo[128 * 32];

    const int t    = threadIdx.x;
    const int wave = t >> 6, lane = t & 63;
    const int wm   = wave >> 1, wn = wave & 1;
    const int n0   = blockIdx.x * 128;
    const int m0   = blockIdx.y * 128;
    const int z    = blockIdx.z;
    const float* X = (z == 0) ? X0 : ((z == 1) ? X1 : X2);
    const unsigned short* Whz = Wthi + (size_t)z * D_MODEL * D_MODEL;
    const unsigned short* Wlz = Wtlo + (size_t)z * D_MODEL * D_MODEL;
    float* outz = out + (size_t)z * MROWS * HEAD_DIM * NB_HEAD / 1;  // z * 4M floats

    f32x4 acc[4][4] = {};

    const int bn = t >> 2;          // B staging: row n within pass (+p*64)
    const int bk = (t & 3) * 8;     // k element offset (8 bf16 = 16 B)
    const int arow = t >> 3;        // A staging: row within pass (+p*32)
    const int acol = (t & 7) * 4;   // k element offset (4 fp32 = 16 B)

    for (int k0 = 0; k0 < D_MODEL; k0 += 32) {
        // ---- A tile: fp32 load + split-convert + ds_write
        #pragma unroll
        for (int p = 0; p < 4; ++p) {
            const int row = p * 32 + arow;
            const float4 v = *(const float4*)(X + (size_t)(m0 + row) * D_MODEL + k0 + acol);
            unsigned short h[4], l[4];
            const float xs[4] = {v.x, v.y, v.z, v.w};
            #pragma unroll
            for (int u = 0; u < 4; ++u) {
                h[u] = f2bf_rn(xs[u]);
                l[u] = f2bf_rn(xs[u] - bf2f(h[u]));
            }
            *(ushort4*)(&Ahi[row * 32 + acol]) = make_ushort4(h[0], h[1], h[2], h[3]);
            *(ushort4*)(&Alo[row * 32 + acol]) = make_ushort4(l[0], l[1], l[2], l[3]);
        }
        // ---- B tile: async global->LDS, width 16
        #pragma unroll
        for (int p = 0; p < 2; ++p) {
            const int n = p * 64 + bn;
            const unsigned short* gh = Whz + (size_t)(n0 + n) * D_MODEL + k0 + bk;
            const unsigned short* gl = Wlz + (size_t)(n0 + n) * D_MODEL + k0 + bk;
            __builtin_amdgcn_global_load_lds(
                (const __attribute__((address_space(1))) void*)gh,
                (__attribute__((address_space(3))) void*)&Bhi[n * 32 + bk], 16, 0, 0);
            __builtin_amdgcn_global_load_lds(
                (const __attribute__((address_space(1))) void*)gl,
                (__attribute__((address_space(3))) void*)&Blo[n * 32 + bk], 16, 0, 0);
        }
        __syncthreads();  // drains vmcnt+lgkmcnt, then barrier

        bf16x8 ah[4], al[4];
        #pragma unroll
        for (int i = 0; i < 4; ++i) {
            const int row = wm * 64 + i * 16 + (lane & 15);
            const int off = row * 32 + (lane >> 4) * 8;
            ah[i] = *(const bf16x8*)(&Ahi[off]);
            al[i] = *(const bf16x8*)(&Alo[off]);
        }
        #pragma unroll
        for (int j = 0; j < 4; ++j) {
            const int nrow = wn * 64 + j * 16 + (lane & 15);
            const int off  = nrow * 32 + (lane >> 4) * 8;
            const bf16x8 bh = *(const bf16x8*)(&Bhi[off]);
            const bf16x8 bl = *(const bf16x8*)(&Blo[off]);
            #pragma unroll
            for (int i = 0; i < 4; ++i) {
                acc[i][j] = __builtin_amdgcn_mfma_f32_16x16x32_bf16(ah[i], bh, acc[i][j], 0, 0, 0);
                acc[i][j] = __builtin_amdgcn_mfma_f32_16x16x32_bf16(ah[i], bl, acc[i][j], 0, 0, 0);
                acc[i][j] = __builtin_amdgcn_mfma_f32_16x16x32_bf16(al[i], bh, acc[i][j], 0, 0, 0);
            }
        }
        __syncthreads();  // all waves done reading LDS before next stage
    }

    // Epilogue: C/D layout col=lane&15, row=(lane>>4)*4+reg; permuted write
    const int cl = lane & 15;
    const int rq = (lane >> 4) * 4;
    #pragma unroll
    for (int j = 0; j < 4; ++j) {
        const int cg = n0 + wn * 64 + j * 16 + cl;
        const int h = cg >> 6, d = cg & 63;
        #pragma unroll
        for (int i = 0; i < 4; ++i) {
            #pragma unroll
            for (int r = 0; r < 4; ++r) {
                const int rg = m0 + wm * 64 + i * 16 + rq + r;
                const int b = rg >> 11, l = rg & (SEQ - 1);
                outz[(((size_t)b * NB_HEAD + h) * SEQ + l) * HEAD_DIM + d] = acc[i][j][r];
            }
        }
    }
}

// ---------------------------------------------------------------------------
// Flash-style attention, fp32 (unchanged from round 1).
// ---------------------------------------------------------------------------
__global__ __launch_bounds__(256) void attn_kernel(
    const float* __restrict__ q, const float* __restrict__ k,
    const float* __restrict__ v, const int* __restrict__ q_len,
    const int* __restrict__ v_len, float* __restrict__ out)
{
    __shared__ __align__(16) float Qs[64][68];
    __shared__ __align__(16) float KVs[64][68];
    __shared__ __align__(16) float Ss[64][68];
    __shared__ float m_row[64], l_row[64], a_row[64];

    const int tid = threadIdx.x;
    const int tx = tid & 15, ty = tid >> 4;
    const int q0 = blockIdx.x * 64;
    const int h  = blockIdx.y;
    const int b  = blockIdx.z;
    const int qlen = q_len[b];
    const int vlen = v_len[b];

    float* outb = out + ((size_t)b * SEQ) * D_MODEL + h * HEAD_DIM + tx * 4;

    if (q0 >= qlen) {
        const float4 z = make_float4(0.f, 0.f, 0.f, 0.f);
        #pragma unroll
        for (int i = 0; i < 4; ++i)
            *(float4*)(outb + (size_t)(q0 + ty * 4 + i) * D_MODEL) = z;
        return;
    }

    const size_t headoff = (((size_t)b * NB_HEAD + h) * SEQ) * HEAD_DIM;
    const float* qb = q + headoff;
    const float* kb = k + headoff;
    const float* vb = v + headoff;

    const int lr = tid >> 2;
    const int lc = (tid & 3) * 16;

    {
        const float* qrow = qb + (size_t)(q0 + lr) * HEAD_DIM + lc;
        #pragma unroll
        for (int u = 0; u < 4; ++u) {
            const float4 t4 = *(const float4*)(qrow + u * 4);
            Qs[lc + u * 4 + 0][lr] = t4.x;
            Qs[lc + u * 4 + 1][lr] = t4.y;
            Qs[lc + u * 4 + 2][lr] = t4.z;
            Qs[lc + u * 4 + 3][lr] = t4.w;
        }
    }
    if (tid < 64) { m_row[tid] = -1e30f; l_row[tid] = 0.f; }

    float o[4][4] = {};
    const int nkt = (vlen + 63) >> 6;

    for (int t = 0; t < nkt; ++t) {
        const int k0 = t * 64;
        __syncthreads();

        {
            const float* krow = kb + (size_t)(k0 + lr) * HEAD_DIM + lc;
            #pragma unroll
            for (int u = 0; u < 4; ++u) {
                const float4 t4 = *(const float4*)(krow + u * 4);
                KVs[lc + u * 4 + 0][lr] = t4.x;
                KVs[lc + u * 4 + 1][lr] = t4.y;
                KVs[lc + u * 4 + 2][lr] = t4.z;
                KVs[lc + u * 4 + 3][lr] = t4.w;
            }
        }
        __syncthreads();

        float s[4][4] = {};
        for (int d = 0; d < 64; ++d) {
            const float4 qv = *(const float4*)(&Qs[d][ty * 4]);
            const float4 kv = *(const float4*)(&KVs[d][tx * 4]);
            const float qa[4] = {qv.x, qv.y, qv.z, qv.w};
            const float ka[4] = {kv.x, kv.y, kv.z, kv.w};
            #pragma unroll
            for (int i = 0; i < 4; ++i)
                #pragma unroll
                for (int j = 0; j < 4; ++j)
                    s[i][j] = fmaf(qa[i], ka[j], s[i][j]);
        }
        #pragma unroll
        for (int i = 0; i < 4; ++i)
            #pragma unroll
            for (int j = 0; j < 4; ++j) {
                float val = s[i][j] * 0.125f;
                if (k0 + tx * 4 + j >= vlen) val = -1e30f;
                Ss[ty * 4 + i][tx * 4 + j] = val;
            }
        __syncthreads();

        {
            const float* vrow = vb + (size_t)(k0 + lr) * HEAD_DIM + lc;
            #pragma unroll
            for (int u = 0; u < 4; ++u)
                *(float4*)(&KVs[lr][lc + u * 4]) = *(const float4*)(vrow + u * 4);
        }

        {
            const int r = tid >> 2;
            const int seg = (tid & 3) * 16;
            float vals[16];
            float mx = -1e30f;
            #pragma unroll
            for (int u = 0; u < 4; ++u) {
                const float4 t4 = *(const float4*)(&Ss[r][seg + u * 4]);
                vals[u * 4 + 0] = t4.x; vals[u * 4 + 1] = t4.y;
                vals[u * 4 + 2] = t4.z; vals[u * 4 + 3] = t4.w;
            }
            #pragma unroll
            for (int u = 0; u < 16; ++u) mx = fmaxf(mx, vals[u]);
            mx = fmaxf(mx, __shfl_xor(mx, 1));
            mx = fmaxf(mx, __shfl_xor(mx, 2));
            const float mold = m_row[r];
            const float mnew = fmaxf(mold, mx);
            float sum = 0.f;
            #pragma unroll
            for (int u = 0; u < 16; ++u) { vals[u] = __expf(vals[u] - mnew); sum += vals[u]; }
            #pragma unroll
            for (int u = 0; u < 4; ++u)
                *(float4*)(&Ss[r][seg + u * 4]) =
                    make_float4(vals[u * 4 + 0], vals[u * 4 + 1], vals[u * 4 + 2], vals[u * 4 + 3]);
            sum += __shfl_xor(sum, 1);
            sum += __shfl_xor(sum, 2);
            if ((tid & 3) == 0) {
                const float alpha = __expf(mold - mnew);
                a_row[r] = alpha;
                l_row[r] = l_row[r] * alpha + sum;
                m_row[r] = mnew;
            }
        }
        __syncthreads();

        {
            const float al[4] = {a_row[ty * 4 + 0], a_row[ty * 4 + 1],
                                 a_row[ty * 4 + 2], a_row[ty * 4 + 3]};
            #pragma unroll
            for (int i = 0; i < 4; ++i)
                #pragma unroll
                for (int j = 0; j < 4; ++j)
                    o[i][j] *= al[i];
            for (int kk = 0; kk < 64; kk += 4) {
                float4 p[4], vv[4];
                #pragma unroll
                for (int i = 0; i < 4; ++i) p[i] = *(const float4*)(&Ss[ty * 4 + i][kk]);
                #pragma unroll
                for (int u = 0; u < 4; ++u) vv[u] = *(const float4*)(&KVs[kk + u][tx * 4]);
                #pragma unroll
                for (int i = 0; i < 4; ++i) {
                    const float pa[4] = {p[i].x, p[i].y, p[i].z, p[i].w};
                    #pragma unroll
                    for (int u = 0; u < 4; ++u) {
                        o[i][0] = fmaf(pa[u], vv[u].x, o[i][0]);
                        o[i][1] = fmaf(pa[u], vv[u].y, o[i][1]);
                        o[i][2] = fmaf(pa[u], vv[u].z, o[i][2]);
                        o[i][3] = fmaf(pa[u], vv[u].w, o[i][3]);
                    }
                }
            }
        }
    }

    #pragma unroll
    for (int i = 0; i < 4; ++i) {
        const int r = ty * 4 + i;
        const int qg = q0 + r;
        float4 r4;
        if (qg < qlen) {
            const float inv = 1.f / l_row[r];
            r4 = make_float4(o[i][0] * inv, o[i][1] * inv, o[i][2] * inv, o[i][3] * inv);
        } else {
            r4 = make_float4(0.f, 0.f, 0.f, 0.f);
        }
        *(float4*)(outb + (size_t)qg * D_MODEL) = r4;
    }
}

extern "C" void kernel_launch(void* const* d_in, const int* in_sizes, int n_in,
                              void* d_out, int out_size, void* d_ws, size_t ws_size,
                              hipStream_t stream)
{
    (void)in_sizes; (void)n_in; (void)out_size; (void)ws_size;
    const float* Q_seq = (const float*)d_in[0];
    const float* K_seq = (const float*)d_in[1];
    const float* V_seq = (const float*)d_in[2];
    const int*   q_len = (const int*)d_in[3];
    const int*   v_len = (const int*)d_in[4];
    const float* WQ    = (const float*)d_in[5];
    const float* WK    = (const float*)d_in[6];
    const float* WV    = (const float*)d_in[7];
    float* out = (float*)d_out;

    // Workspace layout:
    //   qw/kw/vw fp32 [3][B][H][SEQ][64]          = 48 MB
    //   Wt hi bf16 [3][N][K]                      =  6 MB
    //   Wt lo bf16 [3][N][K]                      =  6 MB
    const size_t per = (size_t)BATCH * NB_HEAD * SEQ * HEAD_DIM;  // 4M
    float* qw = (float*)d_ws;
    float* kw = qw + per;
    float* vw = kw + per;
    unsigned short* wthi = (unsigned short*)(vw + per);
    unsigned short* wtlo = wthi + (size_t)3 * D_MODEL * D_MODEL;

    dim3 blk(256);

    dim3 cg(D_MODEL / 64, D_MODEL / 64, 3);  // (16,16,3)
    conv_wt_kernel<<<cg, blk, 0, stream>>>(WQ, WK, WV, wthi, wtlo);

    dim3 pg(D_MODEL / 128, MROWS / 128, 3);  // (8,32,3) = 768 blocks
    proj_mfma_kernel<<<pg, blk, 0, stream>>>(Q_seq, K_seq, V_seq, wthi, wtlo, qw);

    dim3 ag(SEQ / 64, NB_HEAD, BATCH);       // (32,16,2)
    attn_kernel<<<ag, blk, 0, stream>>>(qw, kw, vw, q_len, v_len, out);
}

// Round 3
// 326.613 us; speedup vs baseline: 2.4269x; 1.5681x over previous
//
#include <hip/hip_runtime.h>
#include <cstddef>

#define NB_HEAD 16
#define HEAD_DIM 64
#define D_MODEL 1024
#define BATCH 2
#define SEQ 2048
#define MROWS (BATCH * SEQ)  // 4096

typedef __bf16 bf16x8 __attribute__((ext_vector_type(8)));
typedef __bf16 bf16x4 __attribute__((ext_vector_type(4)));
typedef float  f32x4  __attribute__((ext_vector_type(4)));

static __device__ __forceinline__ void split_bf16(float x, __bf16& h, __bf16& l) {
    h = (__bf16)x;
    l = (__bf16)(x - (float)h);
}

// ---------------------------------------------------------------------------
// W[K][N] fp32 -> Wt_hi[N][K], Wt_lo[N][K] bf16 split, per z in {Q,K,V}.
// ---------------------------------------------------------------------------
__global__ __launch_bounds__(256) void conv_wt_kernel(
    const float* __restrict__ W0, const float* __restrict__ W1,
    const float* __restrict__ W2,
    __bf16* __restrict__ hi, __bf16* __restrict__ lo)
{
    __shared__ float tile[64][65];
    const int t  = threadIdx.x;
    const int k0 = blockIdx.x * 64;
    const int n0 = blockIdx.y * 64;
    const int z  = blockIdx.z;
    const float* W = (z == 0) ? W0 : ((z == 1) ? W1 : W2);
    __bf16* hz = hi + (size_t)z * D_MODEL * D_MODEL;
    __bf16* lz = lo + (size_t)z * D_MODEL * D_MODEL;

    #pragma unroll
    for (int p = 0; p < 4; ++p) {
        const int e = (p * 256 + t) * 4;
        const int r = e >> 6, c = e & 63;
        const float4 v = *(const float4*)(W + (size_t)(k0 + r) * D_MODEL + n0 + c);
        tile[r][c] = v.x; tile[r][c + 1] = v.y; tile[r][c + 2] = v.z; tile[r][c + 3] = v.w;
    }
    __syncthreads();
    #pragma unroll
    for (int p = 0; p < 4; ++p) {
        const int e = (p * 256 + t) * 4;
        const int n = e >> 6, kc = e & 63;
        __bf16 h[4], l[4];
        #pragma unroll
        for (int u = 0; u < 4; ++u) split_bf16(tile[kc + u][n], h[u], l[u]);
        *(bf16x4*)(hz + (size_t)(n0 + n) * D_MODEL + k0 + kc) = (bf16x4){h[0], h[1], h[2], h[3]};
        *(bf16x4*)(lz + (size_t)(n0 + n) * D_MODEL + k0 + kc) = (bf16x4){l[0], l[1], l[2], l[3]};
    }
}

// ---------------------------------------------------------------------------
// Split-bf16 MFMA projection. C = Xhi Whi + Xhi Wlo + Xlo Whi.
// 128x128 tile, BK=32, 4 waves. Outputs bf16 hi/lo in [B][H][L][64] layout.
// ---------------------------------------------------------------------------
__global__ __launch_bounds__(256) void proj_mfma_kernel(
    const float* __restrict__ X0, const float* __restrict__ X1,
    const float* __restrict__ X2,
    const __bf16* __restrict__ Wthi, const __bf16* __restrict__ Wtlo,
    __bf16* __restrict__ qhi, __bf16* __restrict__ qlo,
    __bf16* __restrict__ khi, __bf16* __restrict__ klo,
    __bf16* __restrict__ vhi, __bf16* __restrict__ vlo)
{
    __shared__ __align__(16) __bf16 Ahi[128 * 32];
    __shared__ __align__(16) __bf16 Alo[128 * 32];
    __shared__ __align__(16) __bf16 Bhi[128 * 32];
    __shared__ __align__(16) __bf16 Blo[128 * 32];

    const int t    = threadIdx.x;
    const int wave = t >> 6, lane = t & 63;
    const int wm   = wave >> 1, wn = wave & 1;
    const int n0   = blockIdx.x * 128;
    const int m0   = blockIdx.y * 128;
    const int z    = blockIdx.z;
    const float* X = (z == 0) ? X0 : ((z == 1) ? X1 : X2);
    const __bf16* Whz = Wthi + (size_t)z * D_MODEL * D_MODEL;
    const __bf16* Wlz = Wtlo + (size_t)z * D_MODEL * D_MODEL;

    f32x4 acc[4][4] = {};

    const int bn = t >> 2;          // B staging: row n (+p*64)
    const int bk = (t & 3) * 8;     // k offset (16 B)
    const int arow = t >> 3;        // A staging: row (+p*32)
    const int acol = (t & 7) * 4;   // k offset (4 fp32 = 16 B)

    for (int k0 = 0; k0 < D_MODEL; k0 += 32) {
        #pragma unroll
        for (int p = 0; p < 4; ++p) {
            const int row = p * 32 + arow;
            const float4 v = *(const float4*)(X + (size_t)(m0 + row) * D_MODEL + k0 + acol);
            __bf16 h[4], l[4];
            split_bf16(v.x, h[0], l[0]); split_bf16(v.y, h[1], l[1]);
            split_bf16(v.z, h[2], l[2]); split_bf16(v.w, h[3], l[3]);
            *(bf16x4*)(&Ahi[row * 32 + acol]) = (bf16x4){h[0], h[1], h[2], h[3]};
            *(bf16x4*)(&Alo[row * 32 + acol]) = (bf16x4){l[0], l[1], l[2], l[3]};
        }
        #pragma unroll
        for (int p = 0; p < 2; ++p) {
            const int n = p * 64 + bn;
            const __bf16* gh = Whz + (size_t)(n0 + n) * D_MODEL + k0 + bk;
            const __bf16* gl = Wlz + (size_t)(n0 + n) * D_MODEL + k0 + bk;
            __builtin_amdgcn_global_load_lds(
                (const __attribute__((address_space(1))) void*)gh,
                (__attribute__((address_space(3))) void*)&Bhi[n * 32 + bk], 16, 0, 0);
            __builtin_amdgcn_global_load_lds(
                (const __attribute__((address_space(1))) void*)gl,
                (__attribute__((address_space(3))) void*)&Blo[n * 32 + bk], 16, 0, 0);
        }
        __syncthreads();

        bf16x8 ah[4], al[4];
        #pragma unroll
        for (int i = 0; i < 4; ++i) {
            const int row = wm * 64 + i * 16 + (lane & 15);
            const int off = row * 32 + (lane >> 4) * 8;
            ah[i] = *(const bf16x8*)(&Ahi[off]);
            al[i] = *(const bf16x8*)(&Alo[off]);
        }
        #pragma unroll
        for (int j = 0; j < 4; ++j) {
            const int nrow = wn * 64 + j * 16 + (lane & 15);
            const int off  = nrow * 32 + (lane >> 4) * 8;
            const bf16x8 bh = *(const bf16x8*)(&Bhi[off]);
            const bf16x8 bl = *(const bf16x8*)(&Blo[off]);
            #pragma unroll
            for (int i = 0; i < 4; ++i) {
                acc[i][j] = __builtin_amdgcn_mfma_f32_16x16x32_bf16(ah[i], bh, acc[i][j], 0, 0, 0);
                acc[i][j] = __builtin_amdgcn_mfma_f32_16x16x32_bf16(ah[i], bl, acc[i][j], 0, 0, 0);
                acc[i][j] = __builtin_amdgcn_mfma_f32_16x16x32_bf16(al[i], bh, acc[i][j], 0, 0, 0);
            }
        }
        __syncthreads();
    }

    __bf16 *oh, *ol;
    if (z == 0)      { oh = qhi; ol = qlo; }
    else if (z == 1) { oh = khi; ol = klo; }
    else             { oh = vhi; ol = vlo; }

    const int cl = lane & 15;
    const int rq = (lane >> 4) * 4;
    #pragma unroll
    for (int j = 0; j < 4; ++j) {
        const int cg = n0 + wn * 64 + j * 16 + cl;
        const int hd = cg >> 6, d = cg & 63;
        #pragma unroll
        for (int i = 0; i < 4; ++i) {
            #pragma unroll
            for (int r = 0; r < 4; ++r) {
                const int rg = m0 + wm * 64 + i * 16 + rq + r;
                const int bb = rg >> 11, l = rg & (SEQ - 1);
                const size_t a = (((size_t)bb * NB_HEAD + hd) * SEQ + l) * HEAD_DIM + d;
                __bf16 h_, l_;
                split_bf16(acc[i][j][r], h_, l_);
                oh[a] = h_; ol[a] = l_;
            }
        }
    }
}

// ---------------------------------------------------------------------------
// V [b][h][l][d] bf16 hi/lo -> V^T [b][h][d][SEQ] bf16 hi/lo (LDS transpose)
// ---------------------------------------------------------------------------
__global__ __launch_bounds__(256) void vt_conv_kernel(
    const __bf16* __restrict__ vhi, const __bf16* __restrict__ vlo,
    __bf16* __restrict__ vthi, __bf16* __restrict__ vtlo)
{
    __shared__ __align__(16) __bf16 Th[64][72], Tl[64][72];
    const int t  = threadIdx.x;
    const int l0 = blockIdx.x * 64;
    const int bh = blockIdx.y;
    const int lr = t >> 2, seg = (t & 3) * 16;
    const size_t base = (size_t)bh * SEQ * HEAD_DIM;

    #pragma unroll
    for (int u = 0; u < 2; ++u) {
        const int d0 = seg + u * 8;
        const bf16x8 h8 = *(const bf16x8*)(vhi + base + (size_t)(l0 + lr) * HEAD_DIM + d0);
        const bf16x8 l8 = *(const bf16x8*)(vlo + base + (size_t)(l0 + lr) * HEAD_DIM + d0);
        #pragma unroll
        for (int e = 0; e < 8; ++e) { Th[d0 + e][lr] = h8[e]; Tl[d0 + e][lr] = l8[e]; }
    }
    __syncthreads();
    const int d = t >> 2;
    #pragma unroll
    for (int u = 0; u < 2; ++u) {
        const int ls = seg + u * 8;
        const bf16x8 h8 = *(const bf16x8*)(&Th[d][ls]);
        const bf16x8 l8 = *(const bf16x8*)(&Tl[d][ls]);
        *(bf16x8*)(vthi + ((size_t)bh * HEAD_DIM + d) * SEQ + l0 + ls) = h8;
        *(bf16x8*)(vtlo + ((size_t)bh * HEAD_DIM + d) * SEQ + l0 + ls) = l8;
    }
}

// ---------------------------------------------------------------------------
// MFMA flash attention. Block = 128 queries of one (b,h); 4 waves x 32q.
// QK^T: split Q,K (3 MFMA). PV: P rounded-bf16 with l summed from rounded p
// (normalization cancels P quantization), V split (2 MFMA).
// K/V^T staged via XOR-swizzled global_load_lds; Q frags register-persistent;
// P round-trips a per-wave-private LDS strip (no block barrier needed).
// ---------------------------------------------------------------------------
__global__ __launch_bounds__(256) void attn_mfma_kernel(
    const __bf16* __restrict__ qhi, const __bf16* __restrict__ qlo,
    const __bf16* __restrict__ khi, const __bf16* __restrict__ klo,
    const __bf16* __restrict__ vthi, const __bf16* __restrict__ vtlo,
    const int* __restrict__ q_len, const int* __restrict__ v_len,
    float* __restrict__ out)
{
    __shared__ __align__(16) __bf16 Khi[64 * 64], Klo[64 * 64];
    __shared__ __align__(16) __bf16 Vhi[64 * 64], Vlo[64 * 64];
    __shared__ __align__(16) __bf16 Ps[128][72];

    const int t = threadIdx.x;
    const int wq = t >> 6, lane = t & 63;
    const int grp = lane >> 4, li = lane & 15;
    const int q0 = blockIdx.x * 128;
    const int hh = blockIdx.y, b = blockIdx.z;
    const int qlen = q_len[b], vlen = v_len[b];
    const int bh = b * NB_HEAD + hh;

    if (q0 >= qlen) {  // fully masked chunk: zeros for this head's columns
        const int row = t >> 1, cs = (t & 1) * 32;
        float* o = out + ((size_t)b * SEQ + q0 + row) * D_MODEL + hh * HEAD_DIM + cs;
        const float4 z = make_float4(0.f, 0.f, 0.f, 0.f);
        #pragma unroll
        for (int u = 0; u < 8; ++u) *(float4*)(o + u * 4) = z;
        return;
    }

    const size_t koff = (size_t)bh * SEQ * HEAD_DIM;
    const int qbase = q0 + wq * 32;

    // persistent Q fragments (A-layout: m=li, k=grp*8.. + ks*32)
    bf16x8 qh[2][2], ql[2][2];
    #pragma unroll
    for (int s = 0; s < 2; ++s) {
        #pragma unroll
        for (int ks = 0; ks < 2; ++ks) {
            const size_t a = koff + (size_t)(qbase + s * 16 + li) * HEAD_DIM + ks * 32 + grp * 8;
            qh[s][ks] = *(const bf16x8*)(qhi + a);
            ql[s][ks] = *(const bf16x8*)(qlo + a);
        }
    }

    f32x4 O[2][4] = {};
    float m_s[2][4], l_s[2][4];
    #pragma unroll
    for (int s = 0; s < 2; ++s) {
        #pragma unroll
        for (int r = 0; r < 4; ++r) { m_s[s][r] = -1e30f; l_s[s][r] = 0.f; }
    }

    const int srow = t >> 3, cpos = t & 7;
    const int nkt = (vlen + 63) >> 6;

    for (int tt = 0; tt < nkt; ++tt) {
        const int k0 = tt * 64;
        __syncthreads();  // prior tile's LDS reads complete

        // stage K and V^T tiles (hi/lo), XOR chunk swizzle: phys = chunk^(row&7)
        #pragma unroll
        for (int h2 = 0; h2 < 2; ++h2) {
            const int r = h2 * 32 + srow;
            const int c = cpos ^ (r & 7);
            const size_t gk = koff + (size_t)(k0 + r) * HEAD_DIM + c * 8;
            const size_t gv = ((size_t)bh * HEAD_DIM + r) * SEQ + k0 + c * 8;
            const int dst = h2 * 2048 + t * 8;
            __builtin_amdgcn_global_load_lds(
                (const __attribute__((address_space(1))) void*)(khi + gk),
                (__attribute__((address_space(3))) void*)&Khi[dst], 16, 0, 0);
            __builtin_amdgcn_global_load_lds(
                (const __attribute__((address_space(1))) void*)(klo + gk),
                (__attribute__((address_space(3))) void*)&Klo[dst], 16, 0, 0);
            __builtin_amdgcn_global_load_lds(
                (const __attribute__((address_space(1))) void*)(vthi + gv),
                (__attribute__((address_space(3))) void*)&Vhi[dst], 16, 0, 0);
            __builtin_amdgcn_global_load_lds(
                (const __attribute__((address_space(1))) void*)(vtlo + gv),
                (__attribute__((address_space(3))) void*)&Vlo[dst], 16, 0, 0);
        }
        __syncthreads();  // staging visible (syncthreads drains vmcnt)

        // ---- S = Q K^T (split bf16, 3 MFMA per tile-step)
        f32x4 sacc[2][4] = {};
        #pragma unroll
        for (int ks = 0; ks < 2; ++ks) {
            #pragma unroll
            for (int j = 0; j < 4; ++j) {
                const int off = (j * 16 + li) * 64 + (((ks * 4 + grp) ^ (li & 7)) * 8);
                const bf16x8 kh_ = *(const bf16x8*)&Khi[off];
                const bf16x8 kl_ = *(const bf16x8*)&Klo[off];
                #pragma unroll
                for (int s = 0; s < 2; ++s) {
                    sacc[s][j] = __builtin_amdgcn_mfma_f32_16x16x32_bf16(qh[s][ks], kh_, sacc[s][j], 0, 0, 0);
                    sacc[s][j] = __builtin_amdgcn_mfma_f32_16x16x32_bf16(qh[s][ks], kl_, sacc[s][j], 0, 0, 0);
                    sacc[s][j] = __builtin_amdgcn_mfma_f32_16x16x32_bf16(ql[s][ks], kh_, sacc[s][j], 0, 0, 0);
                }
            }
        }

        // ---- online softmax in registers (C-layout: row=grp*4+r, col=li)
        #pragma unroll
        for (int s = 0; s < 2; ++s) {
            float mx[4] = {-1e30f, -1e30f, -1e30f, -1e30f};
            #pragma unroll
            for (int j = 0; j < 4; ++j) {
                const int key = k0 + j * 16 + li;
                #pragma unroll
                for (int r = 0; r < 4; ++r) {
                    float v = sacc[s][j][r] * 0.125f;
                    if (key >= vlen) v = -1e30f;
                    sacc[s][j][r] = v;
                    mx[r] = fmaxf(mx[r], v);
                }
            }
            #pragma unroll
            for (int r = 0; r < 4; ++r) {
                mx[r] = fmaxf(mx[r], __shfl_xor(mx[r], 1));
                mx[r] = fmaxf(mx[r], __shfl_xor(mx[r], 2));
                mx[r] = fmaxf(mx[r], __shfl_xor(mx[r], 4));
                mx[r] = fmaxf(mx[r], __shfl_xor(mx[r], 8));
            }
            float al[4], sum[4];
            #pragma unroll
            for (int r = 0; r < 4; ++r) {
                const float mn = fmaxf(m_s[s][r], mx[r]);
                al[r] = __expf(m_s[s][r] - mn);
                m_s[s][r] = mn;
                sum[r] = 0.f;
            }
            #pragma unroll
            for (int j = 0; j < 4; ++j) {
                #pragma unroll
                for (int r = 0; r < 4; ++r) {
                    const float p = __expf(sacc[s][j][r] - m_s[s][r]);
                    const __bf16 pb = (__bf16)p;     // rounded P; l uses rounded value
                    sum[r] += (float)pb;
                    Ps[wq * 32 + s * 16 + grp * 4 + r][j * 16 + li] = pb;
                }
            }
            #pragma unroll
            for (int r = 0; r < 4; ++r) {
                sum[r] += __shfl_xor(sum[r], 1);
                sum[r] += __shfl_xor(sum[r], 2);
                sum[r] += __shfl_xor(sum[r], 4);
                sum[r] += __shfl_xor(sum[r], 8);
                l_s[s][r] = l_s[s][r] * al[r] + sum[r];
            }
            #pragma unroll
            for (int j = 0; j < 4; ++j) {
                #pragma unroll
                for (int r = 0; r < 4; ++r) O[s][j][r] *= al[r];
            }
        }
        // wave-private P strip: in-order LDS per wave needs only lgkmcnt drain
        asm volatile("s_waitcnt lgkmcnt(0)" ::: "memory");

        // ---- O += P V (P single bf16, V split: 2 MFMA)
        #pragma unroll
        for (int ks = 0; ks < 2; ++ks) {
            bf16x8 pa[2];
            #pragma unroll
            for (int s = 0; s < 2; ++s)
                pa[s] = *(const bf16x8*)&Ps[wq * 32 + s * 16 + li][ks * 32 + grp * 8];
            #pragma unroll
            for (int j = 0; j < 4; ++j) {
                const int off = (j * 16 + li) * 64 + (((ks * 4 + grp) ^ (li & 7)) * 8);
                const bf16x8 vh_ = *(const bf16x8*)&Vhi[off];
                const bf16x8 vl_ = *(const bf16x8*)&Vlo[off];
                #pragma unroll
                for (int s = 0; s < 2; ++s) {
                    O[s][j] = __builtin_amdgcn_mfma_f32_16x16x32_bf16(pa[s], vh_, O[s][j], 0, 0, 0);
                    O[s][j] = __builtin_amdgcn_mfma_f32_16x16x32_bf16(pa[s], vl_, O[s][j], 0, 0, 0);
                }
            }
        }
    }

    // epilogue: normalize, query mask, store
    #pragma unroll
    for (int s = 0; s < 2; ++s) {
        #pragma unroll
        for (int r = 0; r < 4; ++r) {
            const int q = qbase + s * 16 + grp * 4 + r;
            const float inv = (q < qlen) ? 1.f / l_s[s][r] : 0.f;
            #pragma unroll
            for (int j = 0; j < 4; ++j)
                out[((size_t)b * SEQ + q) * D_MODEL + hh * HEAD_DIM + j * 16 + li] = O[s][j][r] * inv;
        }
    }
}

extern "C" void kernel_launch(void* const* d_in, const int* in_sizes, int n_in,
                              void* d_out, int out_size, void* d_ws, size_t ws_size,
                              hipStream_t stream)
{
    (void)in_sizes; (void)n_in; (void)out_size; (void)ws_size;
    const float* Q_seq = (const float*)d_in[0];
    const float* K_seq = (const float*)d_in[1];
    const float* V_seq = (const float*)d_in[2];
    const int*   q_len = (const int*)d_in[3];
    const int*   v_len = (const int*)d_in[4];
    const float* WQ    = (const float*)d_in[5];
    const float* WK    = (const float*)d_in[6];
    const float* WV    = (const float*)d_in[7];
    float* out = (float*)d_out;

    // Workspace (all __bf16): wt hi/lo 2x3M, then 8 arrays of 4M elems = 76 MB
    const size_t WSZ = (size_t)3 * D_MODEL * D_MODEL;              // 3M
    const size_t PER = (size_t)BATCH * NB_HEAD * SEQ * HEAD_DIM;   // 4M
    __bf16* wthi = (__bf16*)d_ws;
    __bf16* wtlo = wthi + WSZ;
    __bf16* qhi_ = wtlo + WSZ;
    __bf16* qlo_ = qhi_ + PER;
    __bf16* khi_ = qlo_ + PER;
    __bf16* klo_ = khi_ + PER;
    __bf16* vhi_ = klo_ + PER;
    __bf16* vlo_ = vhi_ + PER;
    __bf16* vthi_ = vlo_ + PER;
    __bf16* vtlo_ = vthi_ + PER;

    dim3 blk(256);

    dim3 cg(D_MODEL / 64, D_MODEL / 64, 3);   // (16,16,3)
    conv_wt_kernel<<<cg, blk, 0, stream>>>(WQ, WK, WV, wthi, wtlo);

    dim3 pg(D_MODEL / 128, MROWS / 128, 3);   // (8,32,3)
    proj_mfma_kernel<<<pg, blk, 0, stream>>>(Q_seq, K_seq, V_seq, wthi, wtlo,
                                             qhi_, qlo_, khi_, klo_, vhi_, vlo_);

    dim3 vg(SEQ / 64, BATCH * NB_HEAD);       // (32,32)
    vt_conv_kernel<<<vg, blk, 0, stream>>>(vhi_, vlo_, vthi_, vtlo_);

    dim3 ag(SEQ / 128, NB_HEAD, BATCH);       // (16,16,2)
    attn_mfma_kernel<<<ag, blk, 0, stream>>>(qhi_, qlo_, khi_, klo_, vthi_, vtlo_,
                                             q_len, v_len, out);
}